// Round 10
// baseline (347.200 us; speedup 1.0000x reference)
//
#include <hip/hip_runtime.h>
#include <math.h>

// B=4, T=4096 -> NROWS=16384; D=1024; S=2048; K=8; H=512
#define NROWS 16384
#define DDIM  1024
#define SKEYS 2048
#define KTOP  8
#define HDIM  512

typedef short  s16x8 __attribute__((ext_vector_type(8)));
typedef float  f32x4 __attribute__((ext_vector_type(4)));

#define GL16(g, l) __builtin_amdgcn_global_load_lds(                      \
    (const __attribute__((address_space(1))) void*)(g),                   \
    (__attribute__((address_space(3))) void*)(l), 16, 0, 0)

__device__ __forceinline__ float wave_sum(float v) {
#pragma unroll
    for (int off = 32; off > 0; off >>= 1) v += __shfl_xor(v, off, 64);
    return v;
}

__device__ __forceinline__ unsigned short f2bf(float f) {
    union { float f; unsigned u; } c; c.f = f;
    unsigned u = c.u;
    unsigned r = (u + 0x7FFFu + ((u >> 16) & 1u)) >> 16;
    return (unsigned short)r;
}

__device__ __forceinline__ float gelu_exact(float v) {
    return 0.5f * v * (1.0f + erff(v * 0.7071067811865475f));
}

__device__ __forceinline__ ushort4 cvt4(float4 v) {
    ushort4 o;
    o.x = f2bf(v.x); o.y = f2bf(v.y); o.z = f2bf(v.z); o.w = f2bf(v.w);
    return o;
}

// ---------- fused prep: knorm (block==row) + all fp32->bf16 conversions ----------
// grid MUST be SKEYS (2048) blocks x 256 threads.
__global__ __launch_bounds__(256) void prep_kernel(
        const float* __restrict__ x,   const float* __restrict__ Wq,
        const float* __restrict__ Wo,  const float* __restrict__ mv,
        const float* __restrict__ gW1, const float* __restrict__ mk,
        unsigned short* __restrict__ x_bf, unsigned short* __restrict__ wqcat,
        unsigned short* __restrict__ wo_bf, unsigned short* __restrict__ mv_bf,
        unsigned short* __restrict__ gw1b, unsigned short* __restrict__ kn) {
    int bid = blockIdx.x, t = threadIdx.x;
    // --- knorm for key row `bid` ---
    {
        float4 v = ((const float4*)(mk + (size_t)bid * DDIM))[t];
        float ss = v.x * v.x + v.y * v.y + v.z * v.z + v.w * v.w;
        ss = wave_sum(ss);
        __shared__ float wsum[4];
        if ((t & 63) == 0) wsum[t >> 6] = ss;
        __syncthreads();
        float tot = wsum[0] + wsum[1] + wsum[2] + wsum[3];
        float sc = 1.0f / fmaxf(sqrtf(tot), 1e-12f);
        float4 o = make_float4(v.x * sc, v.y * sc, v.z * sc, v.w * sc);
        ((ushort4*)(kn + (size_t)bid * DDIM))[t] = cvt4(o);
    }
    int gid = bid * 256 + t, stride = gridDim.x * 256;
    for (int i = gid; i < NROWS * DDIM / 4; i += stride)
        ((ushort4*)x_bf)[i] = cvt4(((const float4*)x)[i]);
    for (int i = gid; i < DDIM * DDIM / 4; i += stride)
        ((ushort4*)wqcat)[i] = cvt4(((const float4*)Wq)[i]);
    for (int i = gid; i < HDIM * 2 * DDIM / 4; i += stride) {
        float4 v = ((const float4*)gW1)[i];
        int r = i >> 9, c4 = i & 511;
        if (c4 < 256) ((ushort4*)wqcat)[DDIM * DDIM / 4 + r * 256 + c4] = cvt4(v);
        else          ((ushort4*)gw1b)[r * 256 + (c4 - 256)] = cvt4(v);
    }
    for (int i = gid; i < DDIM * DDIM / 4; i += stride)
        ((ushort4*)wo_bf)[i] = cvt4(((const float4*)Wo)[i]);
    for (int i = gid; i < SKEYS * DDIM / 4; i += stride)
        ((ushort4*)mv_bf)[i] = cvt4(((const float4*)mv)[i]);
}

#define INS8(v_, i_)                                                     \
    do {                                                                 \
        float insv_ = (v_); int insi_ = (i_);                            \
        _Pragma("unroll")                                                \
        for (int p_ = 0; p_ < 8; ++p_) {                                 \
            bool sw_ = insv_ > val[p_];                                  \
            float tv_ = val[p_]; int tix_ = idx[p_];                     \
            val[p_] = sw_ ? insv_ : val[p_];                             \
            idx[p_] = sw_ ? insi_ : idx[p_];                             \
            insv_ = sw_ ? tv_ : insv_; insi_ = sw_ ? tix_ : insi_;       \
        }                                                                \
    } while (0)

// ---------- 128x128 bf16 MFMA GEMM, BK=32, 4 waves, 32KB dbuf LDS ----------
// MODE 0: C -> bf16.  MODE 2: split output, blocks with n0>=nsplit write C2.
// (proven round-7 structure: 2 barriers/K-tile, counted vmcnt(4),
//  chunk^((row>>1)&3) swizzle inverse on gload source + on ds_read)
template<int MODE, int K0, int KTOT>
__global__ __launch_bounds__(256, 3) void gemm128(
        const unsigned short* __restrict__ A0, const unsigned short* __restrict__ A1,
        const unsigned short* __restrict__ Bm, const float* __restrict__ bias,
        unsigned short* __restrict__ Cb, int Ncols,
        unsigned short* __restrict__ C2, int N2cols, int nsplit) {
    __shared__ __align__(16) unsigned short As[2][4096];
    __shared__ __align__(16) unsigned short Bs[2][4096];

    int tid = threadIdx.x, l = tid & 63, wid = tid >> 6;
    int gx = gridDim.x;
    int nwg = gx * gridDim.y;
    int bid = blockIdx.y * gx + blockIdx.x;
    int cpx = nwg >> 3;
    int sbid = (bid & 7) * cpx + (bid >> 3);
    int m0 = (sbid / gx) * 128;
    int n0 = (sbid % gx) * 128;

    int wr = wid >> 1, wc = wid & 1;
    constexpr int K1 = KTOT - K0;
    constexpr int NT = KTOT >> 5;

    f32x4 acc[4][4];
#pragma unroll
    for (int i = 0; i < 4; ++i)
#pragma unroll
        for (int j = 0; j < 4; ++j) acc[i][j] = (f32x4){0.f, 0.f, 0.f, 0.f};

    int srow   = tid >> 2;
    int schunk = (tid & 3) ^ ((srow >> 1) & 3);
    int offA0[2], offA1[2], offB[2];
#pragma unroll
    for (int i = 0; i < 2; ++i) {
        int ra = m0 + i * 64 + srow;
        offA0[i] = ra * K0;
        offA1[i] = ra * K1;
        offB[i]  = (n0 + i * 64 + srow) * KTOT;
    }
    int ldsU = wid * 512;   // 1024B per wave (16 rows x 64B)

#define STAGE(bsel, kt_)                                                       \
    do {                                                                       \
        int gk_ = (kt_) * 32 + schunk * 8;                                     \
        _Pragma("unroll")                                                      \
        for (int i_ = 0; i_ < 2; ++i_) {                                       \
            const unsigned short* ga_ = (K0 == KTOT || gk_ < K0)               \
                ? A0 + offA0[i_] + gk_                                         \
                : A1 + offA1[i_] + (gk_ - K0);                                 \
            GL16(ga_, &As[bsel][i_ * 2048 + ldsU]);                            \
            GL16(Bm + offB[i_] + gk_, &Bs[bsel][i_ * 2048 + ldsU]);            \
        }                                                                      \
    } while (0)

    STAGE(0, 0);

    int frow = l & 15;
    int fp   = (l >> 4) ^ ((frow >> 1) & 3);
    int aoff = (wr * 64 + frow) * 32 + fp * 8;
    int boff = (wc * 64 + frow) * 32 + fp * 8;

#pragma unroll 2
    for (int kt = 0; kt < NT; ++kt) {
        int b = kt & 1;
        if (kt + 1 < NT) {
            STAGE(b ^ 1, kt + 1);
            asm volatile("s_waitcnt vmcnt(4)" ::: "memory");
        } else {
            asm volatile("s_waitcnt vmcnt(0)" ::: "memory");
        }
        __builtin_amdgcn_s_barrier();
        asm volatile("" ::: "memory");

        s16x8 af[4], bfr[4];
#pragma unroll
        for (int mf = 0; mf < 4; ++mf)
            af[mf] = *(const s16x8*)&As[b][aoff + mf * 512];
#pragma unroll
        for (int nf = 0; nf < 4; ++nf)
            bfr[nf] = *(const s16x8*)&Bs[b][boff + nf * 512];

        __builtin_amdgcn_s_setprio(1);
#pragma unroll
        for (int mf = 0; mf < 4; ++mf)
#pragma unroll
            for (int nf = 0; nf < 4; ++nf)
                acc[mf][nf] = __builtin_amdgcn_mfma_f32_16x16x32_bf16(
                    af[mf], bfr[nf], acc[mf][nf], 0, 0, 0);
        __builtin_amdgcn_s_setprio(0);
        asm volatile("" ::: "memory");
        __builtin_amdgcn_s_barrier();
        asm volatile("" ::: "memory");
    }
#undef STAGE

    unsigned short* cptr = Cb;
    int nc = Ncols, cb = n0;
    if (MODE == 2 && n0 >= nsplit) { cptr = C2; nc = N2cols; cb = n0 - nsplit; }

    int crow = (l >> 4) << 2;
    int ccol = l & 15;
#pragma unroll
    for (int mf = 0; mf < 4; ++mf) {
        int gr = m0 + wr * 64 + mf * 16 + crow;
#pragma unroll
        for (int nf = 0; nf < 4; ++nf) {
            int gc = cb + wc * 64 + nf * 16 + ccol;
            f32x4 v = acc[mf][nf];
#pragma unroll
            for (int r2 = 0; r2 < 4; ++r2) {
                float o = v[r2];
                cptr[(size_t)(gr + r2) * nc + gc] = f2bf(o);
            }
        }
    }
    (void)bias;
}

// ---------- mega: qinv + top-8 + softmax + gather + gate + residual ----------
// one wave per row; sims reads fully coalesced (lane l: 8 contiguous ushorts).
__global__ __launch_bounds__(256) void mega_kernel(
        const unsigned short* __restrict__ q_bf,
        const unsigned short* __restrict__ sims,
        const unsigned short* __restrict__ x_bf,
        const unsigned short* __restrict__ xg1,
        const unsigned short* __restrict__ mvo,
        const unsigned short* __restrict__ mvog,
        const float* __restrict__ gb1, const float* __restrict__ gW2,
        const float* __restrict__ gb2, float* __restrict__ out) {
    int wid = threadIdx.x >> 6, l = threadIdx.x & 63;
    int row = blockIdx.x * 4 + wid;

    // --- qinv inline (wave_sum leaves total in all lanes -> qs wave-uniform) ---
    const unsigned short* qp = q_bf + (size_t)row * DDIM + l * 16;
    uint4 qa = *(const uint4*)qp, qb = *(const uint4*)(qp + 8);
    unsigned qw[8] = {qa.x, qa.y, qa.z, qa.w, qb.x, qb.y, qb.z, qb.w};
    float ss = 0.f;
#pragma unroll
    for (int j = 0; j < 8; ++j) {
        float lo = __uint_as_float(qw[j] << 16);
        float hi = __uint_as_float(qw[j] & 0xffff0000u);
        ss += lo * lo + hi * hi;
    }
    ss = wave_sum(ss);
    float qs = 1.0f / fmaxf(sqrtf(ss), 1e-12f);

    // --- top-8 over sims row (coalesced: lane l covers [c*512+l*8, +8)) ---
    const unsigned short* sr = sims + (size_t)row * SKEYS;
    float val[8]; int idx[8];
#pragma unroll
    for (int j = 0; j < 8; ++j) { val[j] = -1e30f; idx[j] = 0; }
#pragma unroll
    for (int c = 0; c < 4; ++c) {
        uint4 raw = *(const uint4*)(sr + c * 512 + l * 8);
        unsigned wsv[4] = {raw.x, raw.y, raw.z, raw.w};
#pragma unroll
        for (int q2 = 0; q2 < 4; ++q2) {
            float lo = __uint_as_float(wsv[q2] << 16);
            float hi = __uint_as_float(wsv[q2] & 0xffff0000u);
            int bi0 = c * 512 + l * 8 + q2 * 2;
            if (lo > val[7]) INS8(lo, bi0);
            if (hi > val[7]) INS8(hi, bi0 + 1);
        }
    }
    float ov[8]; int oi[8];
#pragma unroll
    for (int j = 0; j < 8; ++j) {
        float bv = val[0]; int bl = l;
#pragma unroll
        for (int off = 32; off > 0; off >>= 1) {
            float xv = __shfl_xor(bv, off, 64);
            int   xl = __shfl_xor(bl, off, 64);
            if (xv > bv || (xv == bv && xl < bl)) { bv = xv; bl = xl; }
        }
        int bi = __shfl(idx[0], bl, 64);
        ov[j] = bv; oi[j] = bi;      // wave-uniform
        if (l == bl) {
#pragma unroll
            for (int p = 0; p < 7; ++p) { val[p] = val[p + 1]; idx[p] = idx[p + 1]; }
            val[7] = -1e30f;
        }
    }
    // --- softmax (redundant in all lanes; ov[0] is the max) ---
    float w[KTOP];
    float m = ov[0] * qs, ssum = 0.f;
#pragma unroll
    for (int j = 0; j < 8; ++j) { w[j] = expf(ov[j] * qs - m); ssum += w[j]; }
    float sinv = 1.0f / ssum;
#pragma unroll
    for (int j = 0; j < 8; ++j) w[j] *= sinv;

    // --- gather mvo/mvog + gelu gate + residual ---
    float r2[16], hp[8];
#pragma unroll
    for (int j = 0; j < 16; ++j) r2[j] = 0.f;
#pragma unroll
    for (int j = 0; j < 8; ++j) hp[j] = 0.f;
#pragma unroll
    for (int k = 0; k < KTOP; ++k) {
        float wk = w[k];
        const unsigned short* mo = mvo + (size_t)oi[k] * DDIM + l * 16;
        uint4 a0 = *(const uint4*)mo;
        uint4 a1 = *(const uint4*)(mo + 8);
        const unsigned short* mg = mvog + (size_t)oi[k] * HDIM + l * 8;
        uint4 g0 = *(const uint4*)mg;
        unsigned aw[8] = {a0.x, a0.y, a0.z, a0.w, a1.x, a1.y, a1.z, a1.w};
#pragma unroll
        for (int j = 0; j < 8; ++j) {
            r2[2 * j]     += wk * __uint_as_float(aw[j] << 16);
            r2[2 * j + 1] += wk * __uint_as_float(aw[j] & 0xffff0000u);
        }
        unsigned gw[4] = {g0.x, g0.y, g0.z, g0.w};
#pragma unroll
        for (int j = 0; j < 4; ++j) {
            hp[2 * j]     += wk * __uint_as_float(gw[j] << 16);
            hp[2 * j + 1] += wk * __uint_as_float(gw[j] & 0xffff0000u);
        }
    }
    uint4 xg = *(const uint4*)(xg1 + (size_t)row * HDIM + l * 8);
    unsigned xgw[4] = {xg.x, xg.y, xg.z, xg.w};
    float p = 0.f;
#pragma unroll
    for (int j = 0; j < 4; ++j) {
        float h0 = gelu_exact(hp[2 * j] + __uint_as_float(xgw[j] << 16)
                              + gb1[l * 8 + 2 * j]);
        float h1 = gelu_exact(hp[2 * j + 1] + __uint_as_float(xgw[j] & 0xffff0000u)
                              + gb1[l * 8 + 2 * j + 1]);
        p += h0 * gW2[l * 8 + 2 * j] + h1 * gW2[l * 8 + 2 * j + 1];
    }
    p = wave_sum(p);
    float gate = 1.0f / (1.0f + expf(-(p + gb2[0])));
    const unsigned short* xr = x_bf + (size_t)row * DDIM + l * 16;
    uint4 x0 = *(const uint4*)xr, x1 = *(const uint4*)(xr + 8);
    unsigned xw[8] = {x0.x, x0.y, x0.z, x0.w, x1.x, x1.y, x1.z, x1.w};
    float o[16];
#pragma unroll
    for (int j = 0; j < 8; ++j) {
        o[2 * j]     = __uint_as_float(xw[j] << 16)         + gate * r2[2 * j];
        o[2 * j + 1] = __uint_as_float(xw[j] & 0xffff0000u) + gate * r2[2 * j + 1];
    }
    float4* po = (float4*)(out + (size_t)row * DDIM + l * 16);
    po[0] = make_float4(o[0], o[1], o[2], o[3]);
    po[1] = make_float4(o[4], o[5], o[6], o[7]);
    po[2] = make_float4(o[8], o[9], o[10], o[11]);
    po[3] = make_float4(o[12], o[13], o[14], o[15]);
}

extern "C" void kernel_launch(void* const* d_in, const int* in_sizes, int n_in,
                              void* d_out, int out_size, void* d_ws, size_t ws_size,
                              hipStream_t stream) {
    (void)in_sizes; (void)n_in; (void)out_size; (void)ws_size;
    const float* x   = (const float*)d_in[0];
    const float* mk  = (const float*)d_in[1];
    const float* mv  = (const float*)d_in[2];
    const float* Wq  = (const float*)d_in[3];
    const float* Wo  = (const float*)d_in[4];
    const float* gW1 = (const float*)d_in[5];
    const float* gb1 = (const float*)d_in[6];
    const float* gW2 = (const float*)d_in[7];
    const float* gb2 = (const float*)d_in[8];
    float* out = (float*)d_out;

    // workspace (~170 MB), lifetime-aliased
    char* w = (char*)d_ws;
    unsigned short* x_bf    = (unsigned short*)w;  w += (size_t)NROWS * DDIM * 2;
    unsigned short* q_bf    = (unsigned short*)w;  w += (size_t)NROWS * DDIM * 2;
    unsigned short* xg1_bf  = (unsigned short*)w;  w += (size_t)NROWS * HDIM * 2;
    unsigned short* kn_bf   = (unsigned short*)w;  w += (size_t)SKEYS * DDIM * 2;
    unsigned short* wqcat   = (unsigned short*)w;  w += (size_t)(DDIM + HDIM) * DDIM * 2;
    unsigned short* gw1b_bf = (unsigned short*)w;  w += (size_t)HDIM * DDIM * 2;
    unsigned short* wo_bf   = (unsigned short*)w;  w += (size_t)DDIM * DDIM * 2;
    unsigned short* mv_bf   = (unsigned short*)w;  w += (size_t)SKEYS * DDIM * 2;
    unsigned short* mvo_bf  = (unsigned short*)w;  w += (size_t)SKEYS * DDIM * 2;
    unsigned short* mvog_bf = (unsigned short*)w;  w += (size_t)SKEYS * HDIM * 2;
    unsigned short* sims    = (unsigned short*)w;  w += (size_t)NROWS * SKEYS * 2;

    // 1. all conversions + knorm
    prep_kernel<<<SKEYS, 256, 0, stream>>>(x, Wq, Wo, mv, gW1, mk,
                                           x_bf, wqcat, wo_bf, mv_bf, gw1b_bf, kn_bf);

    // 2. mvo = mv @ Wo^T  [S, D]
    gemm128<0, DDIM, DDIM><<<dim3(DDIM / 128, SKEYS / 128), 256, 0, stream>>>(
        mv_bf, mv_bf, wo_bf, nullptr, mvo_bf, DDIM, nullptr, 0, 0);

    // 3. mvog = mvo @ gW1b^T  [S, H]
    gemm128<0, DDIM, DDIM><<<dim3(HDIM / 128, SKEYS / 128), 256, 0, stream>>>(
        mvo_bf, mvo_bf, gw1b_bf, nullptr, mvog_bf, HDIM, nullptr, 0, 0);

    // 4. [q | xg1] = x @ [Wq ; gW1a]^T  [N, 1536] split at col 1024
    gemm128<2, DDIM, DDIM><<<dim3((DDIM + HDIM) / 128, NROWS / 128), 256, 0, stream>>>(
        x_bf, x_bf, wqcat, nullptr, q_bf, DDIM, xg1_bf, HDIM, DDIM);

    // 5. sims = q @ kn^T  [N, S]
    gemm128<0, DDIM, DDIM><<<dim3(SKEYS / 128, NROWS / 128), 256, 0, stream>>>(
        q_bf, q_bf, kn_bf, nullptr, sims, SKEYS, nullptr, 0, 0);

    // 6. qinv + top-8 + softmax + gather + gate + residual
    mega_kernel<<<NROWS / 4, 256, 0, stream>>>(
        q_bf, sims, x_bf, xg1_bf, mvo_bf, mvog_bf, gb1, gW2, gb2, out);
}

// Round 11
// 299.514 us; speedup vs baseline: 1.1592x; 1.1592x over previous
//
#include <hip/hip_runtime.h>
#include <math.h>

// B=4, T=4096 -> NROWS=16384; D=1024; S=2048; K=8; H=512
#define NROWS 16384
#define DDIM  1024
#define SKEYS 2048
#define KTOP  8
#define HDIM  512

typedef short  s16x8 __attribute__((ext_vector_type(8)));
typedef float  f32x4 __attribute__((ext_vector_type(4)));

#define GL16(g, l) __builtin_amdgcn_global_load_lds(                      \
    (const __attribute__((address_space(1))) void*)(g),                   \
    (__attribute__((address_space(3))) void*)(l), 16, 0, 0)

__device__ __forceinline__ float wave_sum(float v) {
#pragma unroll
    for (int off = 32; off > 0; off >>= 1) v += __shfl_xor(v, off, 64);
    return v;
}

__device__ __forceinline__ unsigned short f2bf(float f) {
    union { float f; unsigned u; } c; c.f = f;
    unsigned u = c.u;
    unsigned r = (u + 0x7FFFu + ((u >> 16) & 1u)) >> 16;
    return (unsigned short)r;
}

__device__ __forceinline__ float gelu_exact(float v) {
    return 0.5f * v * (1.0f + erff(v * 0.7071067811865475f));
}

__device__ __forceinline__ ushort4 cvt4(float4 v) {
    ushort4 o;
    o.x = f2bf(v.x); o.y = f2bf(v.y); o.z = f2bf(v.z); o.w = f2bf(v.w);
    return o;
}

// ---------- fused prep: knorm (block==row) + all fp32->bf16 conversions ----------
// grid MUST be SKEYS (2048) blocks x 256 threads.
__global__ __launch_bounds__(256) void prep_kernel(
        const float* __restrict__ x,   const float* __restrict__ Wq,
        const float* __restrict__ Wo,  const float* __restrict__ mv,
        const float* __restrict__ gW1, const float* __restrict__ mk,
        unsigned short* __restrict__ x_bf, unsigned short* __restrict__ wqcat,
        unsigned short* __restrict__ wo_bf, unsigned short* __restrict__ mv_bf,
        unsigned short* __restrict__ gw1b, unsigned short* __restrict__ kn) {
    int bid = blockIdx.x, t = threadIdx.x;
    {
        float4 v = ((const float4*)(mk + (size_t)bid * DDIM))[t];
        float ss = v.x * v.x + v.y * v.y + v.z * v.z + v.w * v.w;
        ss = wave_sum(ss);
        __shared__ float wsum[4];
        if ((t & 63) == 0) wsum[t >> 6] = ss;
        __syncthreads();
        float tot = wsum[0] + wsum[1] + wsum[2] + wsum[3];
        float sc = 1.0f / fmaxf(sqrtf(tot), 1e-12f);
        float4 o = make_float4(v.x * sc, v.y * sc, v.z * sc, v.w * sc);
        ((ushort4*)(kn + (size_t)bid * DDIM))[t] = cvt4(o);
    }
    int gid = bid * 256 + t, stride = gridDim.x * 256;
    for (int i = gid; i < NROWS * DDIM / 4; i += stride)
        ((ushort4*)x_bf)[i] = cvt4(((const float4*)x)[i]);
    for (int i = gid; i < DDIM * DDIM / 4; i += stride)
        ((ushort4*)wqcat)[i] = cvt4(((const float4*)Wq)[i]);
    for (int i = gid; i < HDIM * 2 * DDIM / 4; i += stride) {
        float4 v = ((const float4*)gW1)[i];
        int r = i >> 9, c4 = i & 511;
        if (c4 < 256) ((ushort4*)wqcat)[DDIM * DDIM / 4 + r * 256 + c4] = cvt4(v);
        else          ((ushort4*)gw1b)[r * 256 + (c4 - 256)] = cvt4(v);
    }
    for (int i = gid; i < DDIM * DDIM / 4; i += stride)
        ((ushort4*)wo_bf)[i] = cvt4(((const float4*)Wo)[i]);
    for (int i = gid; i < SKEYS * DDIM / 4; i += stride)
        ((ushort4*)mv_bf)[i] = cvt4(((const float4*)mv)[i]);
}

// ---------- 128x128 bf16 MFMA GEMM, BK=32, 4 waves, 32KB dbuf LDS ----------
// MODE 0: C -> bf16.  MODE 2: split output (n0>=nsplit -> C2).
// MODE 3: C -> sortable-u16 keys (monotone bf16 order, unsigned compare).
template<int MODE, int K0, int KTOT>
__global__ __launch_bounds__(256, 3) void gemm128(
        const unsigned short* __restrict__ A0, const unsigned short* __restrict__ A1,
        const unsigned short* __restrict__ Bm, const float* __restrict__ bias,
        unsigned short* __restrict__ Cb, int Ncols,
        unsigned short* __restrict__ C2, int N2cols, int nsplit) {
    __shared__ __align__(16) unsigned short As[2][4096];
    __shared__ __align__(16) unsigned short Bs[2][4096];

    int tid = threadIdx.x, l = tid & 63, wid = tid >> 6;
    int gx = gridDim.x;
    int nwg = gx * gridDim.y;
    int bid = blockIdx.y * gx + blockIdx.x;
    int cpx = nwg >> 3;
    int sbid = (bid & 7) * cpx + (bid >> 3);
    int m0 = (sbid / gx) * 128;
    int n0 = (sbid % gx) * 128;

    int wr = wid >> 1, wc = wid & 1;
    constexpr int K1 = KTOT - K0;
    constexpr int NT = KTOT >> 5;

    f32x4 acc[4][4];
#pragma unroll
    for (int i = 0; i < 4; ++i)
#pragma unroll
        for (int j = 0; j < 4; ++j) acc[i][j] = (f32x4){0.f, 0.f, 0.f, 0.f};

    int srow   = tid >> 2;
    int schunk = (tid & 3) ^ ((srow >> 1) & 3);
    int offA0[2], offA1[2], offB[2];
#pragma unroll
    for (int i = 0; i < 2; ++i) {
        int ra = m0 + i * 64 + srow;
        offA0[i] = ra * K0;
        offA1[i] = ra * K1;
        offB[i]  = (n0 + i * 64 + srow) * KTOT;
    }
    int ldsU = wid * 512;   // 1024B per wave (16 rows x 64B)

#define STAGE(bsel, kt_)                                                       \
    do {                                                                       \
        int gk_ = (kt_) * 32 + schunk * 8;                                     \
        _Pragma("unroll")                                                      \
        for (int i_ = 0; i_ < 2; ++i_) {                                       \
            const unsigned short* ga_ = (K0 == KTOT || gk_ < K0)               \
                ? A0 + offA0[i_] + gk_                                         \
                : A1 + offA1[i_] + (gk_ - K0);                                 \
            GL16(ga_, &As[bsel][i_ * 2048 + ldsU]);                            \
            GL16(Bm + offB[i_] + gk_, &Bs[bsel][i_ * 2048 + ldsU]);            \
        }                                                                      \
    } while (0)

    STAGE(0, 0);

    int frow = l & 15;
    int fp   = (l >> 4) ^ ((frow >> 1) & 3);
    int aoff = (wr * 64 + frow) * 32 + fp * 8;
    int boff = (wc * 64 + frow) * 32 + fp * 8;

#pragma unroll 2
    for (int kt = 0; kt < NT; ++kt) {
        int b = kt & 1;
        if (kt + 1 < NT) {
            STAGE(b ^ 1, kt + 1);
            asm volatile("s_waitcnt vmcnt(4)" ::: "memory");
        } else {
            asm volatile("s_waitcnt vmcnt(0)" ::: "memory");
        }
        __builtin_amdgcn_s_barrier();
        asm volatile("" ::: "memory");

        s16x8 af[4], bfr[4];
#pragma unroll
        for (int mf = 0; mf < 4; ++mf)
            af[mf] = *(const s16x8*)&As[b][aoff + mf * 512];
#pragma unroll
        for (int nf = 0; nf < 4; ++nf)
            bfr[nf] = *(const s16x8*)&Bs[b][boff + nf * 512];

        __builtin_amdgcn_s_setprio(1);
#pragma unroll
        for (int mf = 0; mf < 4; ++mf)
#pragma unroll
            for (int nf = 0; nf < 4; ++nf)
                acc[mf][nf] = __builtin_amdgcn_mfma_f32_16x16x32_bf16(
                    af[mf], bfr[nf], acc[mf][nf], 0, 0, 0);
        __builtin_amdgcn_s_setprio(0);
        asm volatile("" ::: "memory");
        __builtin_amdgcn_s_barrier();
        asm volatile("" ::: "memory");
    }
#undef STAGE

    unsigned short* cptr = Cb;
    int nc = Ncols, cb = n0;
    if (MODE == 2 && n0 >= nsplit) { cptr = C2; nc = N2cols; cb = n0 - nsplit; }

    int crow = (l >> 4) << 2;
    int ccol = l & 15;
#pragma unroll
    for (int mf = 0; mf < 4; ++mf) {
        int gr = m0 + wr * 64 + mf * 16 + crow;
#pragma unroll
        for (int nf = 0; nf < 4; ++nf) {
            int gc = cb + wc * 64 + nf * 16 + ccol;
            f32x4 v = acc[mf][nf];
#pragma unroll
            for (int r2 = 0; r2 < 4; ++r2) {
                unsigned short sv = f2bf(v[r2]);
                if (MODE == 3)
                    sv = sv ^ ((sv & 0x8000) ? 0xFFFFu : 0x8000u);
                cptr[(size_t)(gr + r2) * nc + gc] = sv;
            }
        }
    }
    (void)bias;
}

// branch-free descending insert of key into sorted-8 array
#define BINS(arr, xk)                                                     \
    do {                                                                  \
        unsigned cur_ = (xk);                                             \
        _Pragma("unroll")                                                 \
        for (int p_ = 0; p_ < 8; ++p_) {                                  \
            unsigned mx_ = arr[p_] > cur_ ? arr[p_] : cur_;               \
            unsigned mn_ = arr[p_] > cur_ ? cur_ : arr[p_];               \
            arr[p_] = mx_; cur_ = mn_;                                    \
        }                                                                 \
    } while (0)

// ---------- mega: qinv + top-8 (u32 keys) + softmax + gather + gate + residual ----------
__global__ __launch_bounds__(256) void mega_kernel(
        const unsigned short* __restrict__ q_bf,
        const unsigned short* __restrict__ sims,   // sortable-u16 keys
        const unsigned short* __restrict__ x_bf,
        const unsigned short* __restrict__ xg1,
        const unsigned short* __restrict__ mvo,
        const unsigned short* __restrict__ mvog,
        const float* __restrict__ gb1, const float* __restrict__ gW2,
        const float* __restrict__ gb2, float* __restrict__ out) {
    int wid = threadIdx.x >> 6, l = threadIdx.x & 63;
    int row = blockIdx.x * 4 + wid;

    // --- qinv inline ---
    const unsigned short* qp = q_bf + (size_t)row * DDIM + l * 16;
    uint4 qa = *(const uint4*)qp, qb = *(const uint4*)(qp + 8);
    unsigned qw[8] = {qa.x, qa.y, qa.z, qa.w, qb.x, qb.y, qb.z, qb.w};
    float ss = 0.f;
#pragma unroll
    for (int j = 0; j < 8; ++j) {
        float lo = __uint_as_float(qw[j] << 16);
        float hi = __uint_as_float(qw[j] & 0xffff0000u);
        ss += lo * lo + hi * hi;
    }
    ss = wave_sum(ss);
    float qs = 1.0f / fmaxf(sqrtf(ss), 1e-12f);

    // --- top-8: branch-free u32-key selection, 2 independent streams ---
    const unsigned short* sr = sims + (size_t)row * SKEYS;
    unsigned a[8], bb[8];
#pragma unroll
    for (int j = 0; j < 8; ++j) { a[j] = 0u; bb[j] = 0u; }
#pragma unroll
    for (int c = 0; c < 4; ++c) {
        uint4 raw = *(const uint4*)(sr + c * 512 + l * 8);
        unsigned wv[4] = {raw.x, raw.y, raw.z, raw.w};
#pragma unroll
        for (int q2 = 0; q2 < 4; ++q2) {
            unsigned bi0 = (unsigned)(c * 512 + l * 8 + q2 * 2);
            unsigned klo = ((wv[q2] & 0xFFFFu) << 16) | bi0;
            unsigned khi = (wv[q2] & 0xFFFF0000u) | (bi0 + 1);
            if (c < 2) { BINS(a, klo); BINS(a, khi); }
            else       { BINS(bb, klo); BINS(bb, khi); }
        }
    }
#pragma unroll
    for (int j = 0; j < 8; ++j) BINS(a, bb[j]);

    // --- extraction: 8 rounds of wave-wide max (keys unique per wave) ---
    float ov[8]; int oi[8];
#pragma unroll
    for (int j = 0; j < 8; ++j) {
        unsigned best = a[0];
#pragma unroll
        for (int off = 32; off > 0; off >>= 1) {
            unsigned o2 = (unsigned)__shfl_xor((int)best, off, 64);
            best = best > o2 ? best : o2;
        }
        oi[j] = (int)(best & 0xFFFFu);
        unsigned short ks = (unsigned short)(best >> 16);
        unsigned short sv = ks ^ ((ks & 0x8000) ? 0x8000u : 0xFFFFu);
        ov[j] = __uint_as_float(((unsigned)sv) << 16);
        bool hit = (a[0] == best);
#pragma unroll
        for (int p = 0; p < 7; ++p) a[p] = hit ? a[p + 1] : a[p];
        a[7] = hit ? 0u : a[7];
    }

    // --- softmax (wave-uniform; ov[0] is max) ---
    float w[KTOP];
    float m = ov[0] * qs, ssum = 0.f;
#pragma unroll
    for (int j = 0; j < 8; ++j) { w[j] = expf(ov[j] * qs - m); ssum += w[j]; }
    float sinv = 1.0f / ssum;
#pragma unroll
    for (int j = 0; j < 8; ++j) w[j] *= sinv;

    // --- gather mvo/mvog + gelu gate + residual ---
    float r2[16], hp[8];
#pragma unroll
    for (int j = 0; j < 16; ++j) r2[j] = 0.f;
#pragma unroll
    for (int j = 0; j < 8; ++j) hp[j] = 0.f;
#pragma unroll
    for (int k = 0; k < KTOP; ++k) {
        float wk = w[k];
        const unsigned short* mo = mvo + (size_t)oi[k] * DDIM + l * 16;
        uint4 a0 = *(const uint4*)mo;
        uint4 a1 = *(const uint4*)(mo + 8);
        const unsigned short* mg = mvog + (size_t)oi[k] * HDIM + l * 8;
        uint4 g0 = *(const uint4*)mg;
        unsigned aw[8] = {a0.x, a0.y, a0.z, a0.w, a1.x, a1.y, a1.z, a1.w};
#pragma unroll
        for (int j = 0; j < 8; ++j) {
            r2[2 * j]     += wk * __uint_as_float(aw[j] << 16);
            r2[2 * j + 1] += wk * __uint_as_float(aw[j] & 0xffff0000u);
        }
        unsigned gw[4] = {g0.x, g0.y, g0.z, g0.w};
#pragma unroll
        for (int j = 0; j < 4; ++j) {
            hp[2 * j]     += wk * __uint_as_float(gw[j] << 16);
            hp[2 * j + 1] += wk * __uint_as_float(gw[j] & 0xffff0000u);
        }
    }
    uint4 xg = *(const uint4*)(xg1 + (size_t)row * HDIM + l * 8);
    unsigned xgw[4] = {xg.x, xg.y, xg.z, xg.w};
    float p = 0.f;
#pragma unroll
    for (int j = 0; j < 4; ++j) {
        float h0 = gelu_exact(hp[2 * j] + __uint_as_float(xgw[j] << 16)
                              + gb1[l * 8 + 2 * j]);
        float h1 = gelu_exact(hp[2 * j + 1] + __uint_as_float(xgw[j] & 0xffff0000u)
                              + gb1[l * 8 + 2 * j + 1]);
        p += h0 * gW2[l * 8 + 2 * j] + h1 * gW2[l * 8 + 2 * j + 1];
    }
    p = wave_sum(p);
    float gate = 1.0f / (1.0f + expf(-(p + gb2[0])));
    const unsigned short* xr = x_bf + (size_t)row * DDIM + l * 16;
    uint4 x0 = *(const uint4*)xr, x1 = *(const uint4*)(xr + 8);
    unsigned xw[8] = {x0.x, x0.y, x0.z, x0.w, x1.x, x1.y, x1.z, x1.w};
    float o[16];
#pragma unroll
    for (int j = 0; j < 8; ++j) {
        o[2 * j]     = __uint_as_float(xw[j] << 16)         + gate * r2[2 * j];
        o[2 * j + 1] = __uint_as_float(xw[j] & 0xffff0000u) + gate * r2[2 * j + 1];
    }
    float4* po = (float4*)(out + (size_t)row * DDIM + l * 16);
    po[0] = make_float4(o[0], o[1], o[2], o[3]);
    po[1] = make_float4(o[4], o[5], o[6], o[7]);
    po[2] = make_float4(o[8], o[9], o[10], o[11]);
    po[3] = make_float4(o[12], o[13], o[14], o[15]);
}

extern "C" void kernel_launch(void* const* d_in, const int* in_sizes, int n_in,
                              void* d_out, int out_size, void* d_ws, size_t ws_size,
                              hipStream_t stream) {
    (void)in_sizes; (void)n_in; (void)out_size; (void)ws_size;
    const float* x   = (const float*)d_in[0];
    const float* mk  = (const float*)d_in[1];
    const float* mv  = (const float*)d_in[2];
    const float* Wq  = (const float*)d_in[3];
    const float* Wo  = (const float*)d_in[4];
    const float* gW1 = (const float*)d_in[5];
    const float* gb1 = (const float*)d_in[6];
    const float* gW2 = (const float*)d_in[7];
    const float* gb2 = (const float*)d_in[8];
    float* out = (float*)d_out;

    // workspace (~170 MB), lifetime-aliased
    char* w = (char*)d_ws;
    unsigned short* x_bf    = (unsigned short*)w;  w += (size_t)NROWS * DDIM * 2;
    unsigned short* q_bf    = (unsigned short*)w;  w += (size_t)NROWS * DDIM * 2;
    unsigned short* xg1_bf  = (unsigned short*)w;  w += (size_t)NROWS * HDIM * 2;
    unsigned short* kn_bf   = (unsigned short*)w;  w += (size_t)SKEYS * DDIM * 2;
    unsigned short* wqcat   = (unsigned short*)w;  w += (size_t)(DDIM + HDIM) * DDIM * 2;
    unsigned short* gw1b_bf = (unsigned short*)w;  w += (size_t)HDIM * DDIM * 2;
    unsigned short* wo_bf   = (unsigned short*)w;  w += (size_t)DDIM * DDIM * 2;
    unsigned short* mv_bf   = (unsigned short*)w;  w += (size_t)SKEYS * DDIM * 2;
    unsigned short* mvo_bf  = (unsigned short*)w;  w += (size_t)SKEYS * DDIM * 2;
    unsigned short* mvog_bf = (unsigned short*)w;  w += (size_t)SKEYS * HDIM * 2;
    unsigned short* sims    = (unsigned short*)w;  w += (size_t)NROWS * SKEYS * 2;

    // 1. all conversions + knorm
    prep_kernel<<<SKEYS, 256, 0, stream>>>(x, Wq, Wo, mv, gW1, mk,
                                           x_bf, wqcat, wo_bf, mv_bf, gw1b_bf, kn_bf);

    // 2. mvo = mv @ Wo^T  [S, D]
    gemm128<0, DDIM, DDIM><<<dim3(DDIM / 128, SKEYS / 128), 256, 0, stream>>>(
        mv_bf, mv_bf, wo_bf, nullptr, mvo_bf, DDIM, nullptr, 0, 0);

    // 3. mvog = mvo @ gW1b^T  [S, H]
    gemm128<0, DDIM, DDIM><<<dim3(HDIM / 128, SKEYS / 128), 256, 0, stream>>>(
        mvo_bf, mvo_bf, gw1b_bf, nullptr, mvog_bf, HDIM, nullptr, 0, 0);

    // 4. [q | xg1] = x @ [Wq ; gW1a]^T  [N, 1536] split at col 1024
    gemm128<2, DDIM, DDIM><<<dim3((DDIM + HDIM) / 128, NROWS / 128), 256, 0, stream>>>(
        x_bf, x_bf, wqcat, nullptr, q_bf, DDIM, xg1_bf, HDIM, DDIM);

    // 5. sims = q @ kn^T  [N, S]  (sortable-u16 keys)
    gemm128<3, DDIM, DDIM><<<dim3(SKEYS / 128, NROWS / 128), 256, 0, stream>>>(
        q_bf, q_bf, kn_bf, nullptr, sims, SKEYS, nullptr, 0, 0);

    // 6. qinv + top-8 + softmax + gather + gate + residual
    mega_kernel<<<NROWS / 4, 256, 0, stream>>>(
        q_bf, sims, x_bf, xg1_bf, mvo_bf, mvog_bf, gb1, gW2, gb2, out);
}

// Round 12
// 286.331 us; speedup vs baseline: 1.2126x; 1.0460x over previous
//
#include <hip/hip_runtime.h>
#include <math.h>

// B=4, T=4096 -> NROWS=16384; D=1024; S=2048; K=8; H=512
#define NROWS 16384
#define DDIM  1024
#define SKEYS 2048
#define KTOP  8
#define HDIM  512

typedef short  s16x8 __attribute__((ext_vector_type(8)));
typedef float  f32x4 __attribute__((ext_vector_type(4)));

#define GL16(g, l) __builtin_amdgcn_global_load_lds(                      \
    (const __attribute__((address_space(1))) void*)(g),                   \
    (__attribute__((address_space(3))) void*)(l), 16, 0, 0)

__device__ __forceinline__ float wave_sum(float v) {
#pragma unroll
    for (int off = 32; off > 0; off >>= 1) v += __shfl_xor(v, off, 64);
    return v;
}

__device__ __forceinline__ unsigned short f2bf(float f) {
    union { float f; unsigned u; } c; c.f = f;
    unsigned u = c.u;
    unsigned r = (u + 0x7FFFu + ((u >> 16) & 1u)) >> 16;
    return (unsigned short)r;
}

__device__ __forceinline__ float gelu_exact(float v) {
    return 0.5f * v * (1.0f + erff(v * 0.7071067811865475f));
}

__device__ __forceinline__ ushort4 cvt4(float4 v) {
    ushort4 o;
    o.x = f2bf(v.x); o.y = f2bf(v.y); o.z = f2bf(v.z); o.w = f2bf(v.w);
    return o;
}

// ---------- fused prep: knorm (block==row) + all fp32->bf16 conversions ----------
// grid MUST be SKEYS (2048) blocks x 256 threads.
__global__ __launch_bounds__(256) void prep_kernel(
        const float* __restrict__ x,   const float* __restrict__ Wq,
        const float* __restrict__ Wo,  const float* __restrict__ mv,
        const float* __restrict__ gW1, const float* __restrict__ mk,
        unsigned short* __restrict__ x_bf, unsigned short* __restrict__ wqcat,
        unsigned short* __restrict__ wo_bf, unsigned short* __restrict__ mv_bf,
        unsigned short* __restrict__ gw1b, unsigned short* __restrict__ kn) {
    int bid = blockIdx.x, t = threadIdx.x;
    {
        float4 v = ((const float4*)(mk + (size_t)bid * DDIM))[t];
        float ss = v.x * v.x + v.y * v.y + v.z * v.z + v.w * v.w;
        ss = wave_sum(ss);
        __shared__ float wsum[4];
        if ((t & 63) == 0) wsum[t >> 6] = ss;
        __syncthreads();
        float tot = wsum[0] + wsum[1] + wsum[2] + wsum[3];
        float sc = 1.0f / fmaxf(sqrtf(tot), 1e-12f);
        float4 o = make_float4(v.x * sc, v.y * sc, v.z * sc, v.w * sc);
        ((ushort4*)(kn + (size_t)bid * DDIM))[t] = cvt4(o);
    }
    int gid = bid * 256 + t, stride = gridDim.x * 256;
    for (int i = gid; i < NROWS * DDIM / 4; i += stride)
        ((ushort4*)x_bf)[i] = cvt4(((const float4*)x)[i]);
    for (int i = gid; i < DDIM * DDIM / 4; i += stride)
        ((ushort4*)wqcat)[i] = cvt4(((const float4*)Wq)[i]);
    for (int i = gid; i < HDIM * 2 * DDIM / 4; i += stride) {
        float4 v = ((const float4*)gW1)[i];
        int r = i >> 9, c4 = i & 511;
        if (c4 < 256) ((ushort4*)wqcat)[DDIM * DDIM / 4 + r * 256 + c4] = cvt4(v);
        else          ((ushort4*)gw1b)[r * 256 + (c4 - 256)] = cvt4(v);
    }
    for (int i = gid; i < DDIM * DDIM / 4; i += stride)
        ((ushort4*)wo_bf)[i] = cvt4(((const float4*)Wo)[i]);
    for (int i = gid; i < SKEYS * DDIM / 4; i += stride)
        ((ushort4*)mv_bf)[i] = cvt4(((const float4*)mv)[i]);
}

// ---------- dual 128x128 bf16 MFMA GEMM, K=1024 fixed, BK=32, 4 waves ----------
// Two independent GEMMs in one launch, routed by block range.
// mode 0: C -> bf16.  mode 2: split output (n0>=nsplit -> C2) + per-row
// sum-of-squares atomics into qinv for the C (q) region.  mode 3: C ->
// sortable-u16 keys (monotone bf16 order under unsigned compare).
struct GArg {
    const unsigned short* A;
    const unsigned short* B;
    unsigned short* C;
    unsigned short* C2;
    float* qinv;
    int Ncols, N2cols, nsplit, gx, nblocks, mode;
};

__global__ __launch_bounds__(256, 3) void dualgemm(GArg g0, GArg g1, int split) {
    __shared__ __align__(16) unsigned short As[2][4096];
    __shared__ __align__(16) unsigned short Bs[2][4096];

    int tid = threadIdx.x, l = tid & 63, wid = tid >> 6;
    bool first = ((int)blockIdx.x < split);
    GArg g = first ? g0 : g1;
    int bid = first ? blockIdx.x : blockIdx.x - split;
    // XCD-chunked swizzle within this sub-grid (nblocks % 8 == 0)
    int cpx = g.nblocks >> 3;
    int sbid = (bid & 7) * cpx + (bid >> 3);
    int m0 = (sbid / g.gx) * 128;
    int n0 = (sbid % g.gx) * 128;

    int wr = wid >> 1, wc = wid & 1;
    constexpr int NT = 32;   // K = 1024 / 32

    f32x4 acc[4][4];
#pragma unroll
    for (int i = 0; i < 4; ++i)
#pragma unroll
        for (int j = 0; j < 4; ++j) acc[i][j] = (f32x4){0.f, 0.f, 0.f, 0.f};

    int srow   = tid >> 2;
    int schunk = (tid & 3) ^ ((srow >> 1) & 3);
    int offA[2], offB[2];
#pragma unroll
    for (int i = 0; i < 2; ++i) {
        offA[i] = (m0 + i * 64 + srow) * 1024;
        offB[i] = (n0 + i * 64 + srow) * 1024;
    }
    int ldsU = wid * 512;   // 1024B per wave (16 rows x 64B)

#define STAGE(bsel, kt_)                                                       \
    do {                                                                       \
        int gk_ = (kt_) * 32 + schunk * 8;                                     \
        _Pragma("unroll")                                                      \
        for (int i_ = 0; i_ < 2; ++i_) {                                       \
            GL16(g.A + offA[i_] + gk_, &As[bsel][i_ * 2048 + ldsU]);           \
            GL16(g.B + offB[i_] + gk_, &Bs[bsel][i_ * 2048 + ldsU]);           \
        }                                                                      \
    } while (0)

    STAGE(0, 0);

    int frow = l & 15;
    int fp   = (l >> 4) ^ ((frow >> 1) & 3);
    int aoff = (wr * 64 + frow) * 32 + fp * 8;
    int boff = (wc * 64 + frow) * 32 + fp * 8;

#pragma unroll 2
    for (int kt = 0; kt < NT; ++kt) {
        int b = kt & 1;
        if (kt + 1 < NT) {
            STAGE(b ^ 1, kt + 1);
            asm volatile("s_waitcnt vmcnt(4)" ::: "memory");
        } else {
            asm volatile("s_waitcnt vmcnt(0)" ::: "memory");
        }
        __builtin_amdgcn_s_barrier();
        asm volatile("" ::: "memory");

        s16x8 af[4], bfr[4];
#pragma unroll
        for (int mf = 0; mf < 4; ++mf)
            af[mf] = *(const s16x8*)&As[b][aoff + mf * 512];
#pragma unroll
        for (int nf = 0; nf < 4; ++nf)
            bfr[nf] = *(const s16x8*)&Bs[b][boff + nf * 512];

        __builtin_amdgcn_s_setprio(1);
#pragma unroll
        for (int mf = 0; mf < 4; ++mf)
#pragma unroll
            for (int nf = 0; nf < 4; ++nf)
                acc[mf][nf] = __builtin_amdgcn_mfma_f32_16x16x32_bf16(
                    af[mf], bfr[nf], acc[mf][nf], 0, 0, 0);
        __builtin_amdgcn_s_setprio(0);
        asm volatile("" ::: "memory");
        __builtin_amdgcn_s_barrier();
        asm volatile("" ::: "memory");
    }
#undef STAGE

    unsigned short* cptr = g.C;
    int nc = g.Ncols, cb = n0;
    bool qreg = (g.mode == 2);
    if (g.mode == 2 && n0 >= g.nsplit) {
        cptr = g.C2; nc = g.N2cols; cb = n0 - g.nsplit; qreg = false;
    }

    int crow = (l >> 4) << 2;
    int ccol = l & 15;
    float rs[4][4];
#pragma unroll
    for (int i = 0; i < 4; ++i)
#pragma unroll
        for (int j = 0; j < 4; ++j) rs[i][j] = 0.f;

#pragma unroll
    for (int mf = 0; mf < 4; ++mf) {
        int gr = m0 + wr * 64 + mf * 16 + crow;
#pragma unroll
        for (int nf = 0; nf < 4; ++nf) {
            int gc = cb + wc * 64 + nf * 16 + ccol;
            f32x4 v = acc[mf][nf];
#pragma unroll
            for (int r2 = 0; r2 < 4; ++r2) {
                float o = v[r2];
                unsigned short sv = f2bf(o);
                if (g.mode == 3)
                    sv = sv ^ ((sv & 0x8000) ? 0xFFFFu : 0x8000u);
                cptr[(size_t)(gr + r2) * nc + gc] = sv;
                if (qreg) rs[mf][r2] += o * o;
            }
        }
    }
    if (qreg) {
#pragma unroll
        for (int mf = 0; mf < 4; ++mf)
#pragma unroll
            for (int r2 = 0; r2 < 4; ++r2) {
                float s = rs[mf][r2];
                s += __shfl_xor(s, 1, 64);
                s += __shfl_xor(s, 2, 64);
                s += __shfl_xor(s, 4, 64);
                s += __shfl_xor(s, 8, 64);
                if ((l & 15) == 0)
                    atomicAdd(&g.qinv[m0 + wr * 64 + mf * 16 + (l >> 4) * 4 + r2], s);
            }
    }
}

// branch-free descending insert of key into sorted-8 array
#define BINS(arr, xk)                                                     \
    do {                                                                  \
        unsigned cur_ = (xk);                                             \
        _Pragma("unroll")                                                 \
        for (int p_ = 0; p_ < 8; ++p_) {                                  \
            unsigned mx_ = arr[p_] > cur_ ? arr[p_] : cur_;               \
            unsigned mn_ = arr[p_] > cur_ ? cur_ : arr[p_];               \
            arr[p_] = mx_; cur_ = mn_;                                    \
        }                                                                 \
    } while (0)

// ---------- mega: top-8 (u32 keys) + softmax + gather + gate + residual ----------
__global__ __launch_bounds__(256) void mega_kernel(
        const float* __restrict__ qsum,            // per-row sum of squares
        const unsigned short* __restrict__ sims,   // sortable-u16 keys
        const unsigned short* __restrict__ x_bf,
        const unsigned short* __restrict__ xg1,
        const unsigned short* __restrict__ mvo,
        const unsigned short* __restrict__ mvog,
        const float* __restrict__ gb1, const float* __restrict__ gW2,
        const float* __restrict__ gb2, float* __restrict__ out) {
    int wid = threadIdx.x >> 6, l = threadIdx.x & 63;
    int row = blockIdx.x * 4 + wid;

    float qs = 1.0f / fmaxf(sqrtf(qsum[row]), 1e-12f);

    // --- top-8: branch-free u32-key selection, 2 independent streams ---
    const unsigned short* sr = sims + (size_t)row * SKEYS;
    unsigned a[8], bb[8];
#pragma unroll
    for (int j = 0; j < 8; ++j) { a[j] = 0u; bb[j] = 0u; }
#pragma unroll
    for (int c = 0; c < 4; ++c) {
        uint4 raw = *(const uint4*)(sr + c * 512 + l * 8);
        unsigned wv[4] = {raw.x, raw.y, raw.z, raw.w};
#pragma unroll
        for (int q2 = 0; q2 < 4; ++q2) {
            unsigned bi0 = (unsigned)(c * 512 + l * 8 + q2 * 2);
            unsigned klo = ((wv[q2] & 0xFFFFu) << 16) | bi0;
            unsigned khi = (wv[q2] & 0xFFFF0000u) | (bi0 + 1);
            if (c < 2) { BINS(a, klo); BINS(a, khi); }
            else       { BINS(bb, klo); BINS(bb, khi); }
        }
    }
#pragma unroll
    for (int j = 0; j < 8; ++j) BINS(a, bb[j]);

    // --- extraction: 8 rounds of wave-wide max (keys unique per wave) ---
    float ov[8]; int oi[8];
#pragma unroll
    for (int j = 0; j < 8; ++j) {
        unsigned best = a[0];
#pragma unroll
        for (int off = 32; off > 0; off >>= 1) {
            unsigned o2 = (unsigned)__shfl_xor((int)best, off, 64);
            best = best > o2 ? best : o2;
        }
        oi[j] = (int)(best & 0xFFFFu);
        unsigned short ks = (unsigned short)(best >> 16);
        unsigned short sv = ks ^ ((ks & 0x8000) ? 0x8000u : 0xFFFFu);
        ov[j] = __uint_as_float(((unsigned)sv) << 16);
        bool hit = (a[0] == best);
#pragma unroll
        for (int p = 0; p < 7; ++p) a[p] = hit ? a[p + 1] : a[p];
        a[7] = hit ? 0u : a[7];
    }

    // --- softmax (wave-uniform; ov[0] is max) ---
    float w[KTOP];
    float m = ov[0] * qs, ssum = 0.f;
#pragma unroll
    for (int j = 0; j < 8; ++j) { w[j] = expf(ov[j] * qs - m); ssum += w[j]; }
    float sinv = 1.0f / ssum;
#pragma unroll
    for (int j = 0; j < 8; ++j) w[j] *= sinv;

    // --- gather mvo/mvog + gelu gate + residual ---
    float r2[16], hp[8];
#pragma unroll
    for (int j = 0; j < 16; ++j) r2[j] = 0.f;
#pragma unroll
    for (int j = 0; j < 8; ++j) hp[j] = 0.f;
#pragma unroll
    for (int k = 0; k < KTOP; ++k) {
        float wk = w[k];
        const unsigned short* mo = mvo + (size_t)oi[k] * DDIM + l * 16;
        uint4 a0 = *(const uint4*)mo;
        uint4 a1 = *(const uint4*)(mo + 8);
        const unsigned short* mg = mvog + (size_t)oi[k] * HDIM + l * 8;
        uint4 g0 = *(const uint4*)mg;
        unsigned aw[8] = {a0.x, a0.y, a0.z, a0.w, a1.x, a1.y, a1.z, a1.w};
#pragma unroll
        for (int j = 0; j < 8; ++j) {
            r2[2 * j]     += wk * __uint_as_float(aw[j] << 16);
            r2[2 * j + 1] += wk * __uint_as_float(aw[j] & 0xffff0000u);
        }
        unsigned gw[4] = {g0.x, g0.y, g0.z, g0.w};
#pragma unroll
        for (int j = 0; j < 4; ++j) {
            hp[2 * j]     += wk * __uint_as_float(gw[j] << 16);
            hp[2 * j + 1] += wk * __uint_as_float(gw[j] & 0xffff0000u);
        }
    }
    uint4 xg = *(const uint4*)(xg1 + (size_t)row * HDIM + l * 8);
    unsigned xgw[4] = {xg.x, xg.y, xg.z, xg.w};
    float p = 0.f;
#pragma unroll
    for (int j = 0; j < 4; ++j) {
        float h0 = gelu_exact(hp[2 * j] + __uint_as_float(xgw[j] << 16)
                              + gb1[l * 8 + 2 * j]);
        float h1 = gelu_exact(hp[2 * j + 1] + __uint_as_float(xgw[j] & 0xffff0000u)
                              + gb1[l * 8 + 2 * j + 1]);
        p += h0 * gW2[l * 8 + 2 * j] + h1 * gW2[l * 8 + 2 * j + 1];
    }
    p = wave_sum(p);
    float gate = 1.0f / (1.0f + expf(-(p + gb2[0])));
    const unsigned short* xr = x_bf + (size_t)row * DDIM + l * 16;
    uint4 x0 = *(const uint4*)xr, x1 = *(const uint4*)(xr + 8);
    unsigned xw[8] = {x0.x, x0.y, x0.z, x0.w, x1.x, x1.y, x1.z, x1.w};
    float o[16];
#pragma unroll
    for (int j = 0; j < 8; ++j) {
        o[2 * j]     = __uint_as_float(xw[j] << 16)         + gate * r2[2 * j];
        o[2 * j + 1] = __uint_as_float(xw[j] & 0xffff0000u) + gate * r2[2 * j + 1];
    }
    float4* po = (float4*)(out + (size_t)row * DDIM + l * 16);
    po[0] = make_float4(o[0], o[1], o[2], o[3]);
    po[1] = make_float4(o[4], o[5], o[6], o[7]);
    po[2] = make_float4(o[8], o[9], o[10], o[11]);
    po[3] = make_float4(o[12], o[13], o[14], o[15]);
}

extern "C" void kernel_launch(void* const* d_in, const int* in_sizes, int n_in,
                              void* d_out, int out_size, void* d_ws, size_t ws_size,
                              hipStream_t stream) {
    (void)in_sizes; (void)n_in; (void)out_size; (void)ws_size;
    const float* x   = (const float*)d_in[0];
    const float* mk  = (const float*)d_in[1];
    const float* mv  = (const float*)d_in[2];
    const float* Wq  = (const float*)d_in[3];
    const float* Wo  = (const float*)d_in[4];
    const float* gW1 = (const float*)d_in[5];
    const float* gb1 = (const float*)d_in[6];
    const float* gW2 = (const float*)d_in[7];
    const float* gb2 = (const float*)d_in[8];
    float* out = (float*)d_out;

    // workspace (~170 MB), lifetime-aliased
    char* w = (char*)d_ws;
    unsigned short* x_bf    = (unsigned short*)w;  w += (size_t)NROWS * DDIM * 2;
    unsigned short* q_bf    = (unsigned short*)w;  w += (size_t)NROWS * DDIM * 2;
    unsigned short* xg1_bf  = (unsigned short*)w;  w += (size_t)NROWS * HDIM * 2;
    unsigned short* kn_bf   = (unsigned short*)w;  w += (size_t)SKEYS * DDIM * 2;
    unsigned short* wqcat   = (unsigned short*)w;  w += (size_t)(DDIM + HDIM) * DDIM * 2;
    unsigned short* gw1b_bf = (unsigned short*)w;  w += (size_t)HDIM * DDIM * 2;
    unsigned short* wo_bf   = (unsigned short*)w;  w += (size_t)DDIM * DDIM * 2;
    unsigned short* mv_bf   = (unsigned short*)w;  w += (size_t)SKEYS * DDIM * 2;
    unsigned short* mvo_bf  = (unsigned short*)w;  w += (size_t)SKEYS * DDIM * 2;
    unsigned short* mvog_bf = (unsigned short*)w;  w += (size_t)SKEYS * HDIM * 2;
    unsigned short* sims    = (unsigned short*)w;  w += (size_t)NROWS * SKEYS * 2;
    float* qsum = (float*)w;                       w += (size_t)NROWS * 4;

    // 0. zero the qsum accumulator (graph-capture-safe)
    hipMemsetAsync(qsum, 0, (size_t)NROWS * sizeof(float), stream);

    // 1. all conversions + knorm
    prep_kernel<<<SKEYS, 256, 0, stream>>>(x, Wq, Wo, mv, gW1, mk,
                                           x_bf, wqcat, wo_bf, mv_bf, gw1b_bf, kn_bf);

    // 2. dual: [q|xg1] = x @ [Wq;gW1a]^T (+qsum atomics)  ||  mvo = mv @ Wo^T
    {
        GArg gq; gq.A = x_bf;  gq.B = wqcat; gq.C = q_bf;  gq.C2 = xg1_bf;
        gq.qinv = qsum; gq.Ncols = DDIM; gq.N2cols = HDIM; gq.nsplit = DDIM;
        gq.gx = 12; gq.nblocks = 1536; gq.mode = 2;
        GArg gm; gm.A = mv_bf; gm.B = wo_bf; gm.C = mvo_bf; gm.C2 = nullptr;
        gm.qinv = nullptr; gm.Ncols = DDIM; gm.N2cols = 0; gm.nsplit = 0;
        gm.gx = 8; gm.nblocks = 128; gm.mode = 0;
        dualgemm<<<1664, 256, 0, stream>>>(gq, gm, 1536);
    }

    // 3. dual: sims = q @ kn^T (keys)  ||  mvog = mvo @ gW1b^T
    {
        GArg gs; gs.A = q_bf;   gs.B = kn_bf;   gs.C = sims;    gs.C2 = nullptr;
        gs.qinv = nullptr; gs.Ncols = SKEYS; gs.N2cols = 0; gs.nsplit = 0;
        gs.gx = 16; gs.nblocks = 2048; gs.mode = 3;
        GArg gg; gg.A = mvo_bf; gg.B = gw1b_bf; gg.C = mvog_bf; gg.C2 = nullptr;
        gg.qinv = nullptr; gg.Ncols = HDIM; gg.N2cols = 0; gg.nsplit = 0;
        gg.gx = 4; gg.nblocks = 64; gg.mode = 0;
        dualgemm<<<2112, 256, 0, stream>>>(gs, gg, 2048);
    }

    // 4. top-8 + softmax + gather + gate + residual
    mega_kernel<<<NROWS / 4, 256, 0, stream>>>(
        qsum, sims, x_bf, xg1_bf, mvo_bf, mvog_bf, gb1, gW2, gb2, out);
}

// Round 13
// 264.306 us; speedup vs baseline: 1.3136x; 1.0833x over previous
//
#include <hip/hip_runtime.h>
#include <math.h>

// B=4, T=4096 -> NROWS=16384; D=1024; S=2048; K=8; H=512
#define NROWS 16384
#define DDIM  1024
#define SKEYS 2048
#define KTOP  8
#define HDIM  512

typedef short  s16x8 __attribute__((ext_vector_type(8)));
typedef float  f32x4 __attribute__((ext_vector_type(4)));

#define GL16(g, l) __builtin_amdgcn_global_load_lds(                      \
    (const __attribute__((address_space(1))) void*)(g),                   \
    (__attribute__((address_space(3))) void*)(l), 16, 0, 0)

__device__ __forceinline__ float wave_sum(float v) {
#pragma unroll
    for (int off = 32; off > 0; off >>= 1) v += __shfl_xor(v, off, 64);
    return v;
}

__device__ __forceinline__ unsigned short f2bf(float f) {
    union { float f; unsigned u; } c; c.f = f;
    unsigned u = c.u;
    unsigned r = (u + 0x7FFFu + ((u >> 16) & 1u)) >> 16;
    return (unsigned short)r;
}

__device__ __forceinline__ float gelu_exact(float v) {
    return 0.5f * v * (1.0f + erff(v * 0.7071067811865475f));
}

__device__ __forceinline__ ushort4 cvt4(float4 v) {
    ushort4 o;
    o.x = f2bf(v.x); o.y = f2bf(v.y); o.z = f2bf(v.z); o.w = f2bf(v.w);
    return o;
}

// ---------- fused prep: knorm (block==row) + all fp32->bf16 conversions ----------
__global__ __launch_bounds__(256) void prep_kernel(
        const float* __restrict__ x,   const float* __restrict__ Wq,
        const float* __restrict__ Wo,  const float* __restrict__ mv,
        const float* __restrict__ gW1, const float* __restrict__ mk,
        unsigned short* __restrict__ x_bf, unsigned short* __restrict__ wqcat,
        unsigned short* __restrict__ wo_bf, unsigned short* __restrict__ mv_bf,
        unsigned short* __restrict__ gw1b, unsigned short* __restrict__ kn) {
    int bid = blockIdx.x, t = threadIdx.x;
    {
        float4 v = ((const float4*)(mk + (size_t)bid * DDIM))[t];
        float ss = v.x * v.x + v.y * v.y + v.z * v.z + v.w * v.w;
        ss = wave_sum(ss);
        __shared__ float wsum[4];
        if ((t & 63) == 0) wsum[t >> 6] = ss;
        __syncthreads();
        float tot = wsum[0] + wsum[1] + wsum[2] + wsum[3];
        float sc = 1.0f / fmaxf(sqrtf(tot), 1e-12f);
        float4 o = make_float4(v.x * sc, v.y * sc, v.z * sc, v.w * sc);
        ((ushort4*)(kn + (size_t)bid * DDIM))[t] = cvt4(o);
    }
    int gid = bid * 256 + t, stride = gridDim.x * 256;
    for (int i = gid; i < NROWS * DDIM / 4; i += stride)
        ((ushort4*)x_bf)[i] = cvt4(((const float4*)x)[i]);
    for (int i = gid; i < DDIM * DDIM / 4; i += stride)
        ((ushort4*)wqcat)[i] = cvt4(((const float4*)Wq)[i]);
    for (int i = gid; i < HDIM * 2 * DDIM / 4; i += stride) {
        float4 v = ((const float4*)gW1)[i];
        int r = i >> 9, c4 = i & 511;
        if (c4 < 256) ((ushort4*)wqcat)[DDIM * DDIM / 4 + r * 256 + c4] = cvt4(v);
        else          ((ushort4*)gw1b)[r * 256 + (c4 - 256)] = cvt4(v);
    }
    for (int i = gid; i < DDIM * DDIM / 4; i += stride)
        ((ushort4*)wo_bf)[i] = cvt4(((const float4*)Wo)[i]);
    for (int i = gid; i < SKEYS * DDIM / 4; i += stride)
        ((ushort4*)mv_bf)[i] = cvt4(((const float4*)mv)[i]);
}

// ---------- dual 128x128 bf16 MFMA GEMM, K=1024 fixed, BK=32, 4 waves ----------
// mode 0: C -> bf16.  mode 2: split output (n0>=nsplit -> C2) + per-row
// partial sum-of-squares stores into qpart[16][NROWS] for the q region.
// mode 3: C -> sortable-u16 keys.
struct GArg {
    const unsigned short* A;
    const unsigned short* B;
    unsigned short* C;
    unsigned short* C2;
    float* qpart;
    int Ncols, N2cols, nsplit, gx, nblocks, mode;
};

__global__ __launch_bounds__(256, 3) void dualgemm(GArg g0, GArg g1, int split) {
    __shared__ __align__(16) unsigned short As[2][4096];
    __shared__ __align__(16) unsigned short Bs[2][4096];

    int tid = threadIdx.x, l = tid & 63, wid = tid >> 6;
    bool first = ((int)blockIdx.x < split);
    GArg g = first ? g0 : g1;
    int bid = first ? blockIdx.x : blockIdx.x - split;
    int cpx = g.nblocks >> 3;
    int sbid = (bid & 7) * cpx + (bid >> 3);
    int m0 = (sbid / g.gx) * 128;
    int n0 = (sbid % g.gx) * 128;

    int wr = wid >> 1, wc = wid & 1;
    constexpr int NT = 32;   // K = 1024 / 32

    f32x4 acc[4][4];
#pragma unroll
    for (int i = 0; i < 4; ++i)
#pragma unroll
        for (int j = 0; j < 4; ++j) acc[i][j] = (f32x4){0.f, 0.f, 0.f, 0.f};

    int srow   = tid >> 2;
    int schunk = (tid & 3) ^ ((srow >> 1) & 3);
    int offA[2], offB[2];
#pragma unroll
    for (int i = 0; i < 2; ++i) {
        offA[i] = (m0 + i * 64 + srow) * 1024;
        offB[i] = (n0 + i * 64 + srow) * 1024;
    }
    int ldsU = wid * 512;   // 1024B per wave (16 rows x 64B)

#define STAGE(bsel, kt_)                                                       \
    do {                                                                       \
        int gk_ = (kt_) * 32 + schunk * 8;                                     \
        _Pragma("unroll")                                                      \
        for (int i_ = 0; i_ < 2; ++i_) {                                       \
            GL16(g.A + offA[i_] + gk_, &As[bsel][i_ * 2048 + ldsU]);           \
            GL16(g.B + offB[i_] + gk_, &Bs[bsel][i_ * 2048 + ldsU]);           \
        }                                                                      \
    } while (0)

    STAGE(0, 0);

    int frow = l & 15;
    int fp   = (l >> 4) ^ ((frow >> 1) & 3);
    int aoff = (wr * 64 + frow) * 32 + fp * 8;
    int boff = (wc * 64 + frow) * 32 + fp * 8;

#pragma unroll 2
    for (int kt = 0; kt < NT; ++kt) {
        int b = kt & 1;
        if (kt + 1 < NT) {
            STAGE(b ^ 1, kt + 1);
            asm volatile("s_waitcnt vmcnt(4)" ::: "memory");
        } else {
            asm volatile("s_waitcnt vmcnt(0)" ::: "memory");
        }
        __builtin_amdgcn_s_barrier();
        asm volatile("" ::: "memory");

        s16x8 af[4], bfr[4];
#pragma unroll
        for (int mf = 0; mf < 4; ++mf)
            af[mf] = *(const s16x8*)&As[b][aoff + mf * 512];
#pragma unroll
        for (int nf = 0; nf < 4; ++nf)
            bfr[nf] = *(const s16x8*)&Bs[b][boff + nf * 512];

        __builtin_amdgcn_s_setprio(1);
#pragma unroll
        for (int mf = 0; mf < 4; ++mf)
#pragma unroll
            for (int nf = 0; nf < 4; ++nf)
                acc[mf][nf] = __builtin_amdgcn_mfma_f32_16x16x32_bf16(
                    af[mf], bfr[nf], acc[mf][nf], 0, 0, 0);
        __builtin_amdgcn_s_setprio(0);
        asm volatile("" ::: "memory");
        __builtin_amdgcn_s_barrier();
        asm volatile("" ::: "memory");
    }
#undef STAGE

    unsigned short* cptr = g.C;
    int nc = g.Ncols, cb = n0;
    bool qreg = (g.mode == 2);
    if (g.mode == 2 && n0 >= g.nsplit) {
        cptr = g.C2; nc = g.N2cols; cb = n0 - g.nsplit; qreg = false;
    }

    int crow = (l >> 4) << 2;
    int ccol = l & 15;
    float rs[4][4];
#pragma unroll
    for (int i = 0; i < 4; ++i)
#pragma unroll
        for (int j = 0; j < 4; ++j) rs[i][j] = 0.f;

#pragma unroll
    for (int mf = 0; mf < 4; ++mf) {
        int gr = m0 + wr * 64 + mf * 16 + crow;
#pragma unroll
        for (int nf = 0; nf < 4; ++nf) {
            int gc = cb + wc * 64 + nf * 16 + ccol;
            f32x4 v = acc[mf][nf];
#pragma unroll
            for (int r2 = 0; r2 < 4; ++r2) {
                float o = v[r2];
                unsigned short sv = f2bf(o);
                if (g.mode == 3)
                    sv = sv ^ ((sv & 0x8000) ? 0xFFFFu : 0x8000u);
                cptr[(size_t)(gr + r2) * nc + gc] = sv;
                if (qreg) rs[mf][r2] += o * o;
            }
        }
    }
    if (qreg) {
        int slot = (n0 >> 7) * 2 + wc;   // 0..15
#pragma unroll
        for (int mf = 0; mf < 4; ++mf)
#pragma unroll
            for (int r2 = 0; r2 < 4; ++r2) {
                float s = rs[mf][r2];
                s += __shfl_xor(s, 1, 64);
                s += __shfl_xor(s, 2, 64);
                s += __shfl_xor(s, 4, 64);
                s += __shfl_xor(s, 8, 64);
                if ((l & 15) == 0)
                    g.qpart[(size_t)slot * NROWS +
                            (m0 + wr * 64 + mf * 16 + (l >> 4) * 4 + r2)] = s;
            }
    }
}

// ---------- bitonic top-8 helpers (descending, max-first) ----------
#define CED(k, i, j)                                                      \
    { unsigned mx_ = k[i] > k[j] ? k[i] : k[j];                           \
      unsigned mn_ = k[i] > k[j] ? k[j] : k[i];                           \
      k[i] = mx_; k[j] = mn_; }

__device__ __forceinline__ void sort8d(unsigned* k) {
    // Batcher odd-even mergesort, 19 comparators, descending
    CED(k,0,1) CED(k,2,3) CED(k,4,5) CED(k,6,7)
    CED(k,0,2) CED(k,1,3) CED(k,4,6) CED(k,5,7)
    CED(k,1,2) CED(k,5,6)
    CED(k,0,4) CED(k,1,5) CED(k,2,6) CED(k,3,7)
    CED(k,2,4) CED(k,3,5)
    CED(k,1,2) CED(k,3,4) CED(k,5,6)
}

__device__ __forceinline__ void bclean8d(unsigned* t) {
    // sort a bitonic-8 descending: 3 levels
    CED(t,0,4) CED(t,1,5) CED(t,2,6) CED(t,3,7)
    CED(t,0,2) CED(t,1,3) CED(t,4,6) CED(t,5,7)
    CED(t,0,1) CED(t,2,3) CED(t,4,5) CED(t,6,7)
}

// a, b sorted desc -> a = sorted-desc top-8 of the 16
__device__ __forceinline__ void merge8d(unsigned* a, const unsigned* b) {
    unsigned t[8];
#pragma unroll
    for (int i = 0; i < 8; ++i) t[i] = a[i] > b[7 - i] ? a[i] : b[7 - i];
    bclean8d(t);
#pragma unroll
    for (int i = 0; i < 8; ++i) a[i] = t[i];
}

// ---------- mega: top-8 (bitonic) + softmax + gather + gate + residual ----------
__global__ __launch_bounds__(256) void mega_kernel(
        const float* __restrict__ qpart,           // [16][NROWS] partial sumsq
        const unsigned short* __restrict__ sims,   // sortable-u16 keys
        const unsigned short* __restrict__ x_bf,
        const unsigned short* __restrict__ xg1,
        const unsigned short* __restrict__ mvo,
        const unsigned short* __restrict__ mvog,
        const float* __restrict__ gb1, const float* __restrict__ gW2,
        const float* __restrict__ gb2, float* __restrict__ out) {
    int wid = threadIdx.x >> 6, l = threadIdx.x & 63;
    int row = blockIdx.x * 4 + wid;

    // issue independent loads early: sims row, x row, xg1 row, qpart
    const unsigned short* sr = sims + (size_t)row * SKEYS;
    uint4 raw0 = *(const uint4*)(sr + 0 * 512 + l * 8);
    uint4 raw1 = *(const uint4*)(sr + 1 * 512 + l * 8);
    uint4 raw2 = *(const uint4*)(sr + 2 * 512 + l * 8);
    uint4 raw3 = *(const uint4*)(sr + 3 * 512 + l * 8);
    const unsigned short* xr = x_bf + (size_t)row * DDIM + l * 16;
    uint4 x0 = *(const uint4*)xr, x1 = *(const uint4*)(xr + 8);
    uint4 xg = *(const uint4*)(xg1 + (size_t)row * HDIM + l * 8);

    float ssq = 0.f;
#pragma unroll
    for (int j = 0; j < 16; ++j) ssq += qpart[(size_t)j * NROWS + row];
    float qs = 1.0f / fmaxf(sqrtf(ssq), 1e-12f);

    // --- build 32 u32 keys, sort chunks, merge (all per-lane, branch-free) ---
    unsigned key[32];
    {
        unsigned rw[16] = {raw0.x, raw0.y, raw0.z, raw0.w,
                           raw1.x, raw1.y, raw1.z, raw1.w,
                           raw2.x, raw2.y, raw2.z, raw2.w,
                           raw3.x, raw3.y, raw3.z, raw3.w};
#pragma unroll
        for (int c = 0; c < 4; ++c)
#pragma unroll
            for (int q2 = 0; q2 < 4; ++q2) {
                unsigned v = rw[c * 4 + q2];
                unsigned bi0 = (unsigned)(c * 512 + l * 8 + q2 * 2);
                key[c * 8 + q2 * 2]     = ((v & 0xFFFFu) << 16) | bi0;
                key[c * 8 + q2 * 2 + 1] = (v & 0xFFFF0000u) | (bi0 + 1);
            }
    }
    sort8d(key); sort8d(key + 8); sort8d(key + 16); sort8d(key + 24);
    merge8d(key, key + 8);
    merge8d(key + 16, key + 24);
    merge8d(key, key + 16);

    // --- cross-lane bitonic merge: 6 shfl stages -> all lanes hold row top-8 ---
#pragma unroll
    for (int off = 1; off <= 32; off <<= 1) {
        unsigned br[8];
#pragma unroll
        for (int i = 0; i < 8; ++i)
            br[i] = (unsigned)__shfl_xor((int)key[7 - i], off, 64);
        unsigned t[8];
#pragma unroll
        for (int i = 0; i < 8; ++i) t[i] = key[i] > br[i] ? key[i] : br[i];
        bclean8d(t);
#pragma unroll
        for (int i = 0; i < 8; ++i) key[i] = t[i];
    }

    // --- decode + softmax (identical in all lanes; key[0] is max) ---
    float ov[8]; int oi[8];
#pragma unroll
    for (int j = 0; j < 8; ++j) {
        oi[j] = (int)(key[j] & 0xFFFFu);
        unsigned short ks = (unsigned short)(key[j] >> 16);
        unsigned short sv = ks ^ ((ks & 0x8000) ? 0x8000u : 0xFFFFu);
        ov[j] = __uint_as_float(((unsigned)sv) << 16);
    }
    float w[KTOP];
    float m = ov[0] * qs, ssum = 0.f;
#pragma unroll
    for (int j = 0; j < 8; ++j) { w[j] = expf(ov[j] * qs - m); ssum += w[j]; }
    float sinv = 1.0f / ssum;
#pragma unroll
    for (int j = 0; j < 8; ++j) w[j] *= sinv;

    // --- gather mvo/mvog + gelu gate + residual ---
    float r2[16], hp[8];
#pragma unroll
    for (int j = 0; j < 16; ++j) r2[j] = 0.f;
#pragma unroll
    for (int j = 0; j < 8; ++j) hp[j] = 0.f;
#pragma unroll
    for (int k = 0; k < KTOP; ++k) {
        float wk = w[k];
        const unsigned short* mo = mvo + (size_t)oi[k] * DDIM + l * 16;
        uint4 a0 = *(const uint4*)mo;
        uint4 a1 = *(const uint4*)(mo + 8);
        const unsigned short* mg = mvog + (size_t)oi[k] * HDIM + l * 8;
        uint4 g0 = *(const uint4*)mg;
        unsigned aw[8] = {a0.x, a0.y, a0.z, a0.w, a1.x, a1.y, a1.z, a1.w};
#pragma unroll
        for (int j = 0; j < 8; ++j) {
            r2[2 * j]     += wk * __uint_as_float(aw[j] << 16);
            r2[2 * j + 1] += wk * __uint_as_float(aw[j] & 0xffff0000u);
        }
        unsigned gw[4] = {g0.x, g0.y, g0.z, g0.w};
#pragma unroll
        for (int j = 0; j < 4; ++j) {
            hp[2 * j]     += wk * __uint_as_float(gw[j] << 16);
            hp[2 * j + 1] += wk * __uint_as_float(gw[j] & 0xffff0000u);
        }
    }
    unsigned xgw[4] = {xg.x, xg.y, xg.z, xg.w};
    float p = 0.f;
#pragma unroll
    for (int j = 0; j < 4; ++j) {
        float h0 = gelu_exact(hp[2 * j] + __uint_as_float(xgw[j] << 16)
                              + gb1[l * 8 + 2 * j]);
        float h1 = gelu_exact(hp[2 * j + 1] + __uint_as_float(xgw[j] & 0xffff0000u)
                              + gb1[l * 8 + 2 * j + 1]);
        p += h0 * gW2[l * 8 + 2 * j] + h1 * gW2[l * 8 + 2 * j + 1];
    }
    p = wave_sum(p);
    float gate = 1.0f / (1.0f + expf(-(p + gb2[0])));
    unsigned xw[8] = {x0.x, x0.y, x0.z, x0.w, x1.x, x1.y, x1.z, x1.w};
    float o[16];
#pragma unroll
    for (int j = 0; j < 8; ++j) {
        o[2 * j]     = __uint_as_float(xw[j] << 16)         + gate * r2[2 * j];
        o[2 * j + 1] = __uint_as_float(xw[j] & 0xffff0000u) + gate * r2[2 * j + 1];
    }
    float4* po = (float4*)(out + (size_t)row * DDIM + l * 16);
    po[0] = make_float4(o[0], o[1], o[2], o[3]);
    po[1] = make_float4(o[4], o[5], o[6], o[7]);
    po[2] = make_float4(o[8], o[9], o[10], o[11]);
    po[3] = make_float4(o[12], o[13], o[14], o[15]);
}

extern "C" void kernel_launch(void* const* d_in, const int* in_sizes, int n_in,
                              void* d_out, int out_size, void* d_ws, size_t ws_size,
                              hipStream_t stream) {
    (void)in_sizes; (void)n_in; (void)out_size; (void)ws_size;
    const float* x   = (const float*)d_in[0];
    const float* mk  = (const float*)d_in[1];
    const float* mv  = (const float*)d_in[2];
    const float* Wq  = (const float*)d_in[3];
    const float* Wo  = (const float*)d_in[4];
    const float* gW1 = (const float*)d_in[5];
    const float* gb1 = (const float*)d_in[6];
    const float* gW2 = (const float*)d_in[7];
    const float* gb2 = (const float*)d_in[8];
    float* out = (float*)d_out;

    // workspace (~170 MB), lifetime-aliased
    char* w = (char*)d_ws;
    unsigned short* x_bf    = (unsigned short*)w;  w += (size_t)NROWS * DDIM * 2;
    unsigned short* q_bf    = (unsigned short*)w;  w += (size_t)NROWS * DDIM * 2;
    unsigned short* xg1_bf  = (unsigned short*)w;  w += (size_t)NROWS * HDIM * 2;
    unsigned short* kn_bf   = (unsigned short*)w;  w += (size_t)SKEYS * DDIM * 2;
    unsigned short* wqcat   = (unsigned short*)w;  w += (size_t)(DDIM + HDIM) * DDIM * 2;
    unsigned short* gw1b_bf = (unsigned short*)w;  w += (size_t)HDIM * DDIM * 2;
    unsigned short* wo_bf   = (unsigned short*)w;  w += (size_t)DDIM * DDIM * 2;
    unsigned short* mv_bf   = (unsigned short*)w;  w += (size_t)SKEYS * DDIM * 2;
    unsigned short* mvo_bf  = (unsigned short*)w;  w += (size_t)SKEYS * DDIM * 2;
    unsigned short* mvog_bf = (unsigned short*)w;  w += (size_t)SKEYS * HDIM * 2;
    unsigned short* sims    = (unsigned short*)w;  w += (size_t)NROWS * SKEYS * 2;
    float* qpart = (float*)w;                      w += (size_t)16 * NROWS * 4;

    // 1. all conversions + knorm
    prep_kernel<<<SKEYS, 256, 0, stream>>>(x, Wq, Wo, mv, gW1, mk,
                                           x_bf, wqcat, wo_bf, mv_bf, gw1b_bf, kn_bf);

    // 2. dual: [q|xg1] = x @ [Wq;gW1a]^T (+qpart stores)  ||  mvo = mv @ Wo^T
    {
        GArg gq; gq.A = x_bf;  gq.B = wqcat; gq.C = q_bf;  gq.C2 = xg1_bf;
        gq.qpart = qpart; gq.Ncols = DDIM; gq.N2cols = HDIM; gq.nsplit = DDIM;
        gq.gx = 12; gq.nblocks = 1536; gq.mode = 2;
        GArg gm; gm.A = mv_bf; gm.B = wo_bf; gm.C = mvo_bf; gm.C2 = nullptr;
        gm.qpart = nullptr; gm.Ncols = DDIM; gm.N2cols = 0; gm.nsplit = 0;
        gm.gx = 8; gm.nblocks = 128; gm.mode = 0;
        dualgemm<<<1664, 256, 0, stream>>>(gq, gm, 1536);
    }

    // 3. dual: sims = q @ kn^T (keys)  ||  mvog = mvo @ gW1b^T
    {
        GArg gs; gs.A = q_bf;   gs.B = kn_bf;   gs.C = sims;    gs.C2 = nullptr;
        gs.qpart = nullptr; gs.Ncols = SKEYS; gs.N2cols = 0; gs.nsplit = 0;
        gs.gx = 16; gs.nblocks = 2048; gs.mode = 3;
        GArg gg; gg.A = mvo_bf; gg.B = gw1b_bf; gg.C = mvog_bf; gg.C2 = nullptr;
        gg.qpart = nullptr; gg.Ncols = HDIM; gg.N2cols = 0; gg.nsplit = 0;
        gg.gx = 4; gg.nblocks = 64; gg.mode = 0;
        dualgemm<<<2112, 256, 0, stream>>>(gs, gg, 2048);
    }

    // 4. top-8 + softmax + gather + gate + residual
    mega_kernel<<<NROWS / 4, 256, 0, stream>>>(
        qpart, sims, x_bf, xg1_bf, mvo_bf, mvog_bf, gb1, gW2, gb2, out);
}